// Round 4
// baseline (1272.946 us; speedup 1.0000x reference)
//
#include <hip/hip_runtime.h>
#include <math.h>

// ---------------------------------------------------------------------------
// Swin block, fp32 world (confirmed R3: fp32 branch passed, WRITE=103MB).
// 5 kernels, occupancy/weight-stationary restructure:
//   k_qkv : LN1+shift gather + QKV GEMM (weight-stationary, persistent)
//   k_attn: per-window VALU attention (slim LDS -> 3 blocks/CU)
//   k_proj: proj GEMM + reverse-shift scatter + residual -> out (fp32)
//   k_fc1 : LN2 + fc1 GEMM (weight-stationary persistent) + GELU -> h bf16
//   k_fc2 : fc2 GEMM (weight-stationary persistent) + bias + residual, in-place
// ws: [0,205.5MB) qkv bf16 (154MB) then h bf16 (205.5MB); [205.5,257MB) ao.
// ---------------------------------------------------------------------------

typedef unsigned int   u32;
typedef unsigned short u16;
typedef __bf16 bf16_t;
typedef __bf16 bf16x8 __attribute__((ext_vector_type(8)));
typedef float  f32x4  __attribute__((ext_vector_type(4)));

#define KSCALE 0.17677669529663687f   // 1/sqrt(32)

__device__ __forceinline__ float lo2f(u32 u){ u32 v = u << 16;         float f; __builtin_memcpy(&f,&v,4); return f; }
__device__ __forceinline__ float hi2f(u32 u){ u32 v = u & 0xffff0000u; float f; __builtin_memcpy(&f,&v,4); return f; }
__device__ __forceinline__ float b2f(u16 h){ u32 v = (u32)h << 16;     float f; __builtin_memcpy(&f,&v,4); return f; }
__device__ __forceinline__ u16  f2b(float f){ bf16_t h = (bf16_t)f; u16 u; __builtin_memcpy(&u,&h,2); return u; }
__device__ __forceinline__ u32  pack2(float a, float b){ return (u32)f2b(a) | ((u32)f2b(b) << 16); }

// 64 rows x 32 cols x K=128 MFMA. A from sA (stride astr, col off aoff);
// B rows = output cols from sB (pre-offset to col0; stride bstr, col off boff).
// C/D: col=lane&15, row=(lane>>4)*4+reg  [verified R3].
__device__ __forceinline__ void mm64x32g(const u16* sA, int astr, int aoff,
                                         const u16* sB, int bstr, int boff,
                                         int lane, f32x4 (&acc)[4][2])
{
  const int lr = lane & 15, quad = lane >> 4;
  #pragma unroll
  for (int kk = 0; kk < 4; ++kk) {
    const bf16x8 b0 = *(const bf16x8*)(sB + lr * bstr        + boff + kk*32 + quad*8);
    const bf16x8 b1 = *(const bf16x8*)(sB + (16 + lr) * bstr + boff + kk*32 + quad*8);
    #pragma unroll
    for (int mt = 0; mt < 4; ++mt) {
      const bf16x8 a = *(const bf16x8*)(sA + (mt*16 + lr) * astr + aoff + kk*32 + quad*8);
      acc[mt][0] = __builtin_amdgcn_mfma_f32_16x16x32_bf16(a, b0, acc[mt][0], 0, 0, 0);
      acc[mt][1] = __builtin_amdgcn_mfma_f32_16x16x32_bf16(a, b1, acc[mt][1], 0, 0, 0);
    }
  }
}

// ---------------- K1: LN1 + shift gather + QKV GEMM (persistent) ------------
__global__ __launch_bounds__(256, 1) void k_qkv(
    const float* __restrict__ x, const float* __restrict__ n1w, const float* __restrict__ n1b,
    const float* __restrict__ qkvw, const float* __restrict__ qkvb, u16* __restrict__ qkvo)
{
  __shared__ __align__(16) u16 sW[384 * 136];   // 104,448 B
  __shared__ __align__(16) u16 sA[64 * 136];    //  17,408 B
  const int tid = threadIdx.x, wv = tid >> 6, lane = tid & 63;
  const int lr = lane & 15, quad = lane >> 4;

  for (int i = tid; i < 12288; i += 256) {      // qkv_w fp32 -> bf16 LDS
    const int r = i >> 5, c = (i & 31) * 4;
    const float4 v = *(const float4*)(qkvw + (size_t)r * 128 + c);
    uint2 pk; pk.x = pack2(v.x, v.y); pk.y = pack2(v.z, v.w);
    *(uint2*)(sW + r * 136 + c) = pk;
  }
  const float2 w2 = ((const float2*)n1w)[lane], bb2 = ((const float2*)n1b)[lane];
  float bias[3][2];
  #pragma unroll
  for (int g = 0; g < 3; ++g) { bias[g][0] = qkvb[wv*96 + g*32 + lr]; bias[g][1] = qkvb[wv*96 + g*32 + 16 + lr]; }

  for (int tile = blockIdx.x; tile < 3136; tile += 256) {
    for (int r = wv; r < 64; r += 4) {          // LN1 + shift gather (verified map)
      const int t = tile * 64 + r, g = t / 49, l = t - g * 49;
      const int b_ = g >> 6, win = g & 63, wi = win >> 3, wj = win & 7;
      const int ti = l / 7, tj = l - ti * 7;
      int si = wi * 7 + ti + 3; if (si >= 56) si -= 56;
      int sj = wj * 7 + tj + 3; if (sj >= 56) sj -= 56;
      const float2 xv = ((const float2*)x)[((size_t)b_ * 3136 + si * 56 + sj) * 64 + lane];
      float s = xv.x + xv.y, q = xv.x * xv.x + xv.y * xv.y;
      #pragma unroll
      for (int o = 1; o < 64; o <<= 1) { s += __shfl_xor(s, o, 64); q += __shfl_xor(q, o, 64); }
      const float mean = s * (1.f / 128.f);
      const float rs   = rsqrtf(q * (1.f / 128.f) - mean * mean + 1e-5f);
      ((u32*)sA)[r * 68 + lane] = pack2((xv.x - mean) * rs * w2.x + bb2.x,
                                        (xv.y - mean) * rs * w2.y + bb2.y);
    }
    __syncthreads();
    #pragma unroll
    for (int g = 0; g < 3; ++g) {
      f32x4 acc[4][2];
      #pragma unroll
      for (int mt = 0; mt < 4; ++mt) { acc[mt][0] = f32x4{0,0,0,0}; acc[mt][1] = f32x4{0,0,0,0}; }
      mm64x32g(sA, 136, 0, sW + (wv*96 + g*32) * 136, 136, 0, lane, acc);
      #pragma unroll
      for (int mt = 0; mt < 4; ++mt)
        #pragma unroll
        for (int rr = 0; rr < 4; ++rr) {
          const int m = mt * 16 + quad * 4 + rr;
          #pragma unroll
          for (int nt = 0; nt < 2; ++nt) {
            const int col = wv*96 + g*32 + nt*16 + lr;
            qkvo[(size_t)(tile * 64 + m) * 384 + col] = f2b(acc[mt][nt][rr] + bias[g][nt]);
          }
        }
    }
    __syncthreads();                            // before next tile overwrites sA
  }
}

// ---------------- K2: per-window VALU attention (3 blocks/CU) ---------------
__global__ __launch_bounds__(256, 3) void k_attn(
    const u16* __restrict__ qkv, const float* __restrict__ relb, u16* __restrict__ ao)
{
  __shared__ __align__(16) u16 sQKV[49 * 392]; // [l][q|k|v 384] +8 pad
  __shared__ __align__(16) u16 sAO[49 * 132];
  __shared__ __align__(16) u16 sRB[680];
  const int g = blockIdx.x, tid = threadIdx.x;
  const int hh = tid >> 6, lane = tid & 63;
  const int win = g & 63, wi = win >> 3, wj = win & 7;

  for (int i = tid; i < 676; i += 256) sRB[i] = f2b(relb[i]);
  for (int i = tid; i < 2352; i += 256) {       // 49 rows x 48 uint4
    const int r = i / 48, c = i - r * 48;
    *(uint4*)(sQKV + r * 392 + c * 8) = *(const uint4*)(qkv + ((size_t)g * 49 + r) * 384 + c * 8);
  }
  __syncthreads();

  if (lane < 49) {
    const int l = lane, ti = l / 7, tj = l - ti * 7;
    float q[32];
    {
      const u32* qp = (const u32*)sQKV + l * 196 + hh * 16;
      #pragma unroll
      for (int i = 0; i < 16; ++i) { u32 u = qp[i]; q[2*i] = lo2f(u); q[2*i+1] = hi2f(u); }
    }
    const int regl = ((wi == 7) ? (ti < 4 ? 1 : 2) : 0) * 3 + ((wj == 7) ? (tj < 4 ? 1 : 2) : 0);
    float s[49];
    #pragma unroll
    for (int m = 0; m < 49; ++m) {
      const u32* kp = (const u32*)sQKV + m * 196 + 64 + hh * 16;
      float a = 0.f;
      #pragma unroll
      for (int i = 0; i < 16; ++i) { u32 u = kp[i]; a = fmaf(q[2*i], lo2f(u), a); a = fmaf(q[2*i+1], hi2f(u), a); }
      const int mi = m / 7, mj = m - mi * 7;
      const int regm = ((wi == 7) ? (mi < 4 ? 1 : 2) : 0) * 3 + ((wj == 7) ? (mj < 4 ? 1 : 2) : 0);
      float v = a * KSCALE + b2f(sRB[((ti - mi + 6) * 13 + (tj - mj + 6)) * 4 + hh]);
      if (regl != regm) v -= 100.f;
      s[m] = v;
    }
    float mx = s[0];
    #pragma unroll
    for (int m = 1; m < 49; ++m) mx = fmaxf(mx, s[m]);
    float sum = 0.f;
    #pragma unroll
    for (int m = 0; m < 49; ++m) { float e = __expf(s[m] - mx); s[m] = e; sum += e; }
    const float inv = 1.f / sum;
    float o[32];
    #pragma unroll
    for (int d = 0; d < 32; ++d) o[d] = 0.f;
    #pragma unroll
    for (int m = 0; m < 49; ++m) {
      const float p = s[m];
      const u32* vp = (const u32*)sQKV + m * 196 + 128 + hh * 16;
      #pragma unroll
      for (int i = 0; i < 16; ++i) { u32 u = vp[i]; o[2*i] = fmaf(p, lo2f(u), o[2*i]); o[2*i+1] = fmaf(p, hi2f(u), o[2*i+1]); }
    }
    u32* aop = (u32*)sAO + l * 66 + hh * 16;
    #pragma unroll
    for (int i = 0; i < 16; ++i) aop[i] = pack2(o[2*i] * inv, o[2*i+1] * inv);
  }
  __syncthreads();
  for (int i = tid; i < 3136; i += 256) {       // coalesced store 49x128 bf16
    const int r = i >> 6, c = i & 63;
    ((u32*)ao)[((size_t)g * 49 + r) * 64 + c] = ((const u32*)sAO)[r * 66 + c];
  }
}

// ---------------- K3: proj + reverse-shift scatter + residual ---------------
__global__ __launch_bounds__(256, 3) void k_proj(
    const u16* __restrict__ ao, const float* __restrict__ projw, const float* __restrict__ projb,
    const float* __restrict__ x, float* __restrict__ out)
{
  __shared__ __align__(16) u16 sW[128 * 136];
  __shared__ __align__(16) u16 sA[64 * 136];
  const int blkm = blockIdx.x, tid = threadIdx.x;
  const int wv = tid >> 6, lane = tid & 63, lr = lane & 15, quad = lane >> 4;

  for (int i = tid; i < 4096; i += 256) {
    const int r = i >> 5, c = (i & 31) * 4;
    const float4 v = *(const float4*)(projw + (size_t)r * 128 + c);
    uint2 pk; pk.x = pack2(v.x, v.y); pk.y = pack2(v.z, v.w);
    *(uint2*)(sW + r * 136 + c) = pk;
  }
  for (int i = tid; i < 1024; i += 256) {
    const int r = i >> 4, c8 = (i & 15) * 8;
    *(uint4*)(sA + r * 136 + c8) = *(const uint4*)(ao + ((size_t)blkm * 64 + r) * 128 + c8);
  }
  __syncthreads();
  f32x4 acc[4][2];
  #pragma unroll
  for (int mt = 0; mt < 4; ++mt) { acc[mt][0] = f32x4{0,0,0,0}; acc[mt][1] = f32x4{0,0,0,0}; }
  mm64x32g(sA, 136, 0, sW + (wv*32) * 136, 136, 0, lane, acc);
  const float b0 = projb[wv*32 + lr], b1 = projb[wv*32 + 16 + lr];
  #pragma unroll
  for (int mt = 0; mt < 4; ++mt)
    #pragma unroll
    for (int rr = 0; rr < 4; ++rr) {
      const int m = mt * 16 + quad * 4 + rr, t = blkm * 64 + m;
      const int g = t / 49, l = t - g * 49;
      const int b_ = g >> 6, win = g & 63, wi = win >> 3, wj = win & 7;
      const int ti = l / 7, tj = l - ti * 7;
      int si = wi * 7 + ti + 3; if (si >= 56) si -= 56;
      int sj = wj * 7 + tj + 3; if (sj >= 56) sj -= 56;
      const size_t tok = (size_t)b_ * 3136 + si * 56 + sj;
      #pragma unroll
      for (int nt = 0; nt < 2; ++nt) {
        const int n = wv*32 + nt*16 + lr;
        out[tok * 128 + n] = acc[mt][nt][rr] + (nt ? b1 : b0) + x[tok * 128 + n];
      }
    }
}

// ---------------- K4: LN2 + fc1 + GELU (weight-stationary persistent) -------
__global__ __launch_bounds__(256, 1) void k_fc1(
    const float* __restrict__ xr, const float* __restrict__ n2w, const float* __restrict__ n2b,
    const float* __restrict__ fc1w, const float* __restrict__ fc1b, u16* __restrict__ h)
{
  __shared__ __align__(16) u16 sW[512 * 136];   // 139,264 B
  __shared__ __align__(16) u16 sA[64 * 136];    //  17,408 B
  const int tid = threadIdx.x, wv = tid >> 6, lane = tid & 63;
  const int lr = lane & 15, quad = lane >> 4;

  for (int i = tid; i < 16384; i += 256) {
    const int r = i >> 5, c = (i & 31) * 4;
    const float4 v = *(const float4*)(fc1w + (size_t)r * 128 + c);
    uint2 pk; pk.x = pack2(v.x, v.y); pk.y = pack2(v.z, v.w);
    *(uint2*)(sW + r * 136 + c) = pk;
  }
  const float2 w2 = ((const float2*)n2w)[lane], bb2 = ((const float2*)n2b)[lane];
  float bias[4][2];
  #pragma unroll
  for (int gg = 0; gg < 4; ++gg) { bias[gg][0] = fc1b[wv*128 + gg*32 + lr]; bias[gg][1] = fc1b[wv*128 + gg*32 + 16 + lr]; }

  for (int tile = blockIdx.x; tile < 3136; tile += 256) {
    for (int r = wv; r < 64; r += 4) {          // LN2
      const float2 xv = ((const float2*)xr)[((size_t)tile * 64 + r) * 64 + lane];
      float s = xv.x + xv.y, q = xv.x * xv.x + xv.y * xv.y;
      #pragma unroll
      for (int o = 1; o < 64; o <<= 1) { s += __shfl_xor(s, o, 64); q += __shfl_xor(q, o, 64); }
      const float mean = s * (1.f / 128.f);
      const float rs   = rsqrtf(q * (1.f / 128.f) - mean * mean + 1e-5f);
      ((u32*)sA)[r * 68 + lane] = pack2((xv.x - mean) * rs * w2.x + bb2.x,
                                        (xv.y - mean) * rs * w2.y + bb2.y);
    }
    __syncthreads();
    #pragma unroll
    for (int gg = 0; gg < 4; ++gg) {
      f32x4 acc[4][2];
      #pragma unroll
      for (int mt = 0; mt < 4; ++mt) { acc[mt][0] = f32x4{0,0,0,0}; acc[mt][1] = f32x4{0,0,0,0}; }
      mm64x32g(sA, 136, 0, sW + (wv*128 + gg*32) * 136, 136, 0, lane, acc);
      #pragma unroll
      for (int mt = 0; mt < 4; ++mt)
        #pragma unroll
        for (int rr = 0; rr < 4; ++rr) {
          const int m = mt * 16 + quad * 4 + rr;
          #pragma unroll
          for (int nt = 0; nt < 2; ++nt) {
            const int col = wv*128 + gg*32 + nt*16 + lr;
            float v = acc[mt][nt][rr] + bias[gg][nt];
            // tanh-approx GELU (|err| vs erf-GELU < 1e-3, harmless at thr 0.109)
            const float u_ = 0.7978845608f * (v + 0.044715f * v * v * v);
            const float e  = __expf(-2.f * fabsf(u_));
            float th = (1.f - e) / (1.f + e);
            th = (u_ < 0.f) ? -th : th;
            h[(size_t)(tile * 64 + m) * 512 + col] = f2b(0.5f * v * (1.f + th));
          }
        }
    }
    __syncthreads();
  }
}

// ---------------- K5: fc2 + bias + residual, in-place -----------------------
__global__ __launch_bounds__(256, 1) void k_fc2(
    const u16* __restrict__ h, const float* __restrict__ fc2w, const float* __restrict__ fc2b,
    float* __restrict__ out)
{
  __shared__ __align__(16) u16 sW[128 * 520];   // 133,120 B (N,K) K=512
  __shared__ __align__(16) u16 sA[64 * 136];
  const int tid = threadIdx.x, wv = tid >> 6, lane = tid & 63;
  const int lr = lane & 15, quad = lane >> 4;

  for (int i = tid; i < 16384; i += 256) {
    const int r = i >> 7, c = (i & 127) * 4;
    const float4 v = *(const float4*)(fc2w + (size_t)r * 512 + c);
    uint2 pk; pk.x = pack2(v.x, v.y); pk.y = pack2(v.z, v.w);
    *(uint2*)(sW + r * 520 + c) = pk;
  }
  const float b0 = fc2b[wv*32 + lr], b1 = fc2b[wv*32 + 16 + lr];

  for (int tile = blockIdx.x; tile < 3136; tile += 256) {
    f32x4 acc[4][2];
    #pragma unroll
    for (int mt = 0; mt < 4; ++mt) { acc[mt][0] = f32x4{0,0,0,0}; acc[mt][1] = f32x4{0,0,0,0}; }
    for (int ch = 0; ch < 4; ++ch) {
      for (int i = tid; i < 1024; i += 256) {
        const int r = i >> 4, c8 = (i & 15) * 8;
        *(uint4*)(sA + r * 136 + c8) = *(const uint4*)(h + ((size_t)tile * 64 + r) * 512 + ch * 128 + c8);
      }
      __syncthreads();
      mm64x32g(sA, 136, 0, sW + (wv*32) * 520, 520, ch * 128, lane, acc);
      __syncthreads();
    }
    #pragma unroll
    for (int mt = 0; mt < 4; ++mt)
      #pragma unroll
      for (int rr = 0; rr < 4; ++rr) {
        const int m = mt * 16 + quad * 4 + rr;
        #pragma unroll
        for (int nt = 0; nt < 2; ++nt) {
          const int n = wv*32 + nt*16 + lr;
          const size_t idx = (size_t)(tile * 64 + m) * 128 + n;
          out[idx] = acc[mt][nt][rr] + (nt ? b1 : b0) + out[idx];
        }
      }
  }
}

// ---------------------------------------------------------------------------
extern "C" void kernel_launch(void* const* d_in, const int* in_sizes, int n_in,
                              void* d_out, int out_size, void* d_ws, size_t ws_size,
                              hipStream_t stream) {
  const float* x     = (const float*)d_in[0];
  const float* n1w   = (const float*)d_in[1];
  const float* n1b   = (const float*)d_in[2];
  const float* qkvw  = (const float*)d_in[3];
  const float* qkvb  = (const float*)d_in[4];
  const float* projw = (const float*)d_in[5];
  const float* projb = (const float*)d_in[6];
  const float* relb  = (const float*)d_in[7];
  const float* n2w   = (const float*)d_in[8];
  const float* n2b   = (const float*)d_in[9];
  const float* fc1w  = (const float*)d_in[10];
  const float* fc1b  = (const float*)d_in[11];
  const float* fc2w  = (const float*)d_in[12];
  const float* fc2b  = (const float*)d_in[13];
  float* out = (float*)d_out;

  char* ws = (char*)d_ws;
  u16* qkvo = (u16*)ws;                     // 154,140,672 B
  u16* h    = (u16*)ws;                     // 205,520,896 B (reuses qkvo after k_attn)
  u16* ao   = (u16*)(ws + 205520896);       //  51,380,224 B

  k_qkv <<<dim3(256),  dim3(256), 0, stream>>>(x, n1w, n1b, qkvw, qkvb, qkvo);
  k_attn<<<dim3(4096), dim3(256), 0, stream>>>(qkvo, relb, ao);
  k_proj<<<dim3(3136), dim3(256), 0, stream>>>(ao, projw, projb, x, out);
  k_fc1 <<<dim3(256),  dim3(256), 0, stream>>>(out, n2w, n2b, fc1w, fc1b, h);
  k_fc2 <<<dim3(256),  dim3(256), 0, stream>>>(h, fc2w, fc2b, out);
}